// Round 7
// baseline (6105.495 us; speedup 1.0000x reference)
//
#include <hip/hip_runtime.h>
#include <hip/hip_bf16.h>
#include <stdint.h>
#include <stddef.h>

#define N_NODES 100000
#define N_EDGES 1600000
#define FEAT 128
#define NB_SCAN ((N_NODES + 255) / 256)   // 391 blocks of 256 for the scan
#define NS 16                             // column slices
#define SLW 6250                          // slice width (N_NODES/16); 1.6 MB of features

typedef __attribute__((ext_vector_type(8))) short bf16x8;
typedef __attribute__((ext_vector_type(4))) float f32x4;
typedef unsigned short u16;

__device__ __forceinline__ float bf2f(u16 u) {
    union { unsigned int i; float f; } v; v.i = ((unsigned int)u) << 16; return v.f;
}
__device__ __forceinline__ u16 f2bf(float f) {
    union { float f; unsigned int i; } v; v.f = f;
    unsigned int x = v.i;
    return (u16)((x + 0x7fffu + ((x >> 16) & 1u)) >> 16);   // round-nearest-even
}

// ---------------- CSR build ----------------

__global__ void hist_kernel(const int* __restrict__ rows, int* __restrict__ counts) {
    int e = blockIdx.x * blockDim.x + threadIdx.x;
    if (e < N_EDGES) {
        int r = rows[e];
        r = min(max(r, 0), N_NODES - 1);
        atomicAdd(&counts[r], 1);
    }
}

__global__ void reduce_counts_kernel(const int* __restrict__ counts, int* __restrict__ bsum) {
    __shared__ int s[256];
    int i = blockIdx.x * 256 + threadIdx.x;
    int v = (i < N_NODES) ? counts[i] : 0;
    s[threadIdx.x] = v; __syncthreads();
    for (int off = 128; off > 0; off >>= 1) {
        if (threadIdx.x < off) s[threadIdx.x] += s[threadIdx.x + off];
        __syncthreads();
    }
    if (threadIdx.x == 0) bsum[blockIdx.x] = s[0];
}

__global__ void scan_bsums_kernel(int* __restrict__ bsum, int* __restrict__ row_ptr) {
    __shared__ int s[512];
    int t = threadIdx.x;
    int v = (t < NB_SCAN) ? bsum[t] : 0;
    s[t] = v; __syncthreads();
    for (int off = 1; off < 512; off <<= 1) {
        int x = (t >= off) ? s[t - off] : 0;
        __syncthreads();
        s[t] += x;
        __syncthreads();
    }
    if (t < NB_SCAN) bsum[t] = s[t] - v;              // exclusive
    if (t == NB_SCAN - 1) row_ptr[N_NODES] = s[t];    // total (= N_EDGES)
}

// also zeroes counts so it can be reused as the scatter fill array
__global__ void write_rowptr_kernel(int* __restrict__ counts, const int* __restrict__ bsum,
                                    int* __restrict__ row_ptr) {
    __shared__ int s[256];
    int i = blockIdx.x * 256 + threadIdx.x;
    int v = (i < N_NODES) ? counts[i] : 0;
    s[threadIdx.x] = v; __syncthreads();
    for (int off = 1; off < 256; off <<= 1) {
        int x = (threadIdx.x >= off) ? s[threadIdx.x - off] : 0;
        __syncthreads();
        s[threadIdx.x] += x;
        __syncthreads();
    }
    if (i < N_NODES) {
        row_ptr[i] = bsum[blockIdx.x] + s[threadIdx.x] - v;  // exclusive
        counts[i] = 0;                                       // becomes fill[]
    }
}

__global__ void scatter_kernel(const int* __restrict__ rows, const int* __restrict__ cols,
                               const float* __restrict__ w, const int* __restrict__ row_ptr,
                               int* __restrict__ fill, int* __restrict__ ecol,
                               u16* __restrict__ ewb) {
    int e = blockIdx.x * blockDim.x + threadIdx.x;
    if (e < N_EDGES) {
        int r = rows[e];
        r = min(max(r, 0), N_NODES - 1);
        int pos = row_ptr[r] + atomicAdd(&fill[r], 1);
        pos = min(max(pos, 0), N_EDGES - 1);
        int c = cols[e];
        c = min(max(c, 0), N_NODES - 1);
        ecol[pos] = c;
        ewb[pos] = f2bf(w[e]);
    }
}

// -------- per-row col-sort (64-lane bitonic) + per-slice counts ----------
// Sorting is ONLY a locality optimization; slice counts must sum to deg.

__global__ __launch_bounds__(256) void rowsort_kernel(const int* __restrict__ row_ptr,
                                                      int* __restrict__ ecol,
                                                      u16* __restrict__ ewb,
                                                      u16* __restrict__ scnt) {
    int wave = (blockIdx.x * blockDim.x + threadIdx.x) >> 6;
    int lane = threadIdx.x & 63;
    if (wave >= N_NODES) return;
    int s = row_ptr[wave], e = row_ptr[wave + 1];
    int deg = e - s;
    if (deg <= 64) {
        int c = 0x7fffffff; int wv = 0;
        if (lane < deg) { c = ecol[s + lane]; wv = ewb[s + lane]; }
#pragma unroll
        for (int k = 2; k <= 64; k <<= 1) {
#pragma unroll
            for (int j = k >> 1; j >= 1; j >>= 1) {
                int pc = __shfl_xor(c, j);
                int pw = __shfl_xor(wv, j);
                bool takemin = (((lane & k) == 0) == ((lane & j) == 0));
                bool sw = takemin ? (pc < c) : (pc > c);
                if (sw) { c = pc; wv = pw; }
            }
        }
        if (lane < deg) { ecol[s + lane] = c; ewb[s + lane] = (u16)wv; }
        int sid = (lane < deg) ? min(c / SLW, NS - 1) : -1;
#pragma unroll
        for (int t = 0; t < NS; ++t) {
            unsigned long long m = __ballot(sid == t);
            if (lane == 0) scnt[(size_t)wave * NS + t] = (u16)__popcll(m);
        }
    } else {
        // pathological degree: no sort, dump everything in slice 0 (correct, slower)
        if (lane == 0) {
            scnt[(size_t)wave * NS + 0] = (u16)deg;
            for (int t = 1; t < NS; ++t) scnt[(size_t)wave * NS + t] = 0;
        }
    }
}

// -------- weight prep: W' = [W0-W2 | W1 | 2*W2], f32 -> bf16 ----------

__global__ void prep_w_kernel(const float* __restrict__ W, u16* __restrict__ Wp, int O) {
    int i = blockIdx.x * blockDim.x + threadIdx.x;
    if (i >= O * 384) return;
    int o = i / 384, k = i % 384;
    float v;
    if (k < 128)      v = W[o * 384 + k] - W[o * 384 + 256 + k];
    else if (k < 256) v = W[o * 384 + k];
    else              v = 2.0f * W[o * 384 + k];
    Wp[i] = f2bf(v);
}

// -------- x (f32) -> bf16, 4 elems per thread ----------

__global__ void cvt_kernel(const float* __restrict__ x, u16* __restrict__ y) {
    int i = blockIdx.x * blockDim.x + threadIdx.x;
    if (i >= N_NODES * FEAT / 4) return;
    float4 v = ((const float4*)x)[i];
    ushort4 o;
    o.x = f2bf(v.x); o.y = f2bf(v.y); o.z = f2bf(v.z); o.w = f2bf(v.w);
    ((ushort4*)y)[i] = o;
}

// -------- slice-swept SpMM: Y = A * X  (bf16 in/out, f32 acc) --------------
// One wave owns 32 rows (acc in VGPRs). All co-resident waves sweep column
// slices 0..15 in lockstep-ish order -> the active 1.6MB feature window is
// L2-resident. Per edge: 2 uniform loads + one coalesced 256B row load
// (64 lanes x 4B), no cross-lane reduction. 100000 = 32*3125 rows exactly.

__global__ __launch_bounds__(256, 3) void sweep_kernel(const int* __restrict__ row_ptr,
                                                       const u16* __restrict__ scnt,
                                                       const int* __restrict__ ecol,
                                                       const u16* __restrict__ ewb,
                                                       const u16* __restrict__ X,
                                                       u16* __restrict__ Y) {
    int wv = (blockIdx.x * blockDim.x + threadIdx.x) >> 6;
    int lane = threadIdx.x & 63;
    int r0 = wv * 32;
    if (r0 >= N_NODES) return;

    float acc[32][2];
    int cur[32];
#pragma unroll
    for (int i = 0; i < 32; ++i) {
        acc[i][0] = 0.f; acc[i][1] = 0.f;
        cur[i] = row_ptr[r0 + i];
    }

    for (int s = 0; s < NS; ++s) {
#pragma unroll
        for (int i = 0; i < 32; ++i) {
            int n = scnt[(size_t)(r0 + i) * NS + s];
            int b = cur[i];
            for (int p = 0; p < n; ++p) {
                int c = ecol[b + p];
                float wvv = bf2f(ewb[b + p]);
                unsigned int xv = ((const unsigned int*)(X + (size_t)c * FEAT))[lane];
                acc[i][0] += wvv * bf2f((u16)(xv & 0xffffu));
                acc[i][1] += wvv * bf2f((u16)(xv >> 16));
            }
            cur[i] = b + n;
        }
    }

#pragma unroll
    for (int i = 0; i < 32; ++i) {
        unsigned int o = ((unsigned int)f2bf(acc[i][1]) << 16) | (unsigned int)f2bf(acc[i][0]);
        ((unsigned int*)(Y + (size_t)(r0 + i) * FEAT))[lane] = o;
    }
}

// ------- plain GEMM: out = act( H@W0' + T1@W1' + S2@W2' + b [+H] ) --------
// One block = one 16-row tile, 4 waves each computing O/64 column-tiles.
// __syncthreads between fragment loads and stores makes in-place (out==H,
// out overlapping S2) safe.

template <int O, bool RELU, bool RES, bool OUT_F32>
__global__ __launch_bounds__(256) void gemm_kernel(const u16* __restrict__ H,
                                                   const u16* __restrict__ T1,
                                                   const u16* __restrict__ S2,
                                                   const u16* __restrict__ Wp,
                                                   const float* __restrict__ bias,
                                                   void* __restrict__ outv) {
    int wid = threadIdx.x >> 6, lane = threadIdx.x & 63;
    int m0 = blockIdx.x * 16;
    int r = lane & 15, q = lane >> 4;
    constexpr int NT = O / 16;
    constexpr int NW = NT / 4;          // 2 for O=128, 1 for O=64
    f32x4 acc[NW];
#pragma unroll
    for (int t = 0; t < NW; ++t) acc[t] = (f32x4){0.f, 0.f, 0.f, 0.f};

#pragma unroll
    for (int kk = 0; kk < 12; ++kk) {
        const u16* A = (kk < 4) ? H : (kk < 8 ? T1 : S2);
        bf16x8 af = *(const bf16x8*)(A + (size_t)(m0 + r) * FEAT + (kk & 3) * 32 + q * 8);
#pragma unroll
        for (int t = 0; t < NW; ++t) {
            int ot = wid * NW + t;
            bf16x8 bfr = *(const bf16x8*)(Wp + (size_t)(ot * 16 + r) * 384 + kk * 32 + q * 8);
            acc[t] = __builtin_amdgcn_mfma_f32_16x16x32_bf16(af, bfr, acc[t], 0, 0, 0);
        }
    }

    float hres[NW][4];
    if (RES) {
#pragma unroll
        for (int t = 0; t < NW; ++t) {
            int col = (wid * NW + t) * 16 + r;
#pragma unroll
            for (int i = 0; i < 4; ++i)
                hres[t][i] = bf2f(H[(size_t)(m0 + q * 4 + i) * FEAT + col]);
        }
    }
    __syncthreads();   // all A-fragment (and residual) reads complete before any store

#pragma unroll
    for (int t = 0; t < NW; ++t) {
        int col = (wid * NW + t) * 16 + r;
        float bv = bias[col];
#pragma unroll
        for (int i = 0; i < 4; ++i) {
            int row = m0 + q * 4 + i;
            float v = acc[t][i] + bv;
            if (RES)  v += hres[t][i];
            if (RELU) v = fmaxf(v, 0.f);
            if (OUT_F32) ((float*)outv)[(size_t)row * O + col] = v;
            else         ((u16*)outv)[(size_t)row * O + col] = f2bf(v);
        }
    }
}

// ---------------- launcher ----------------

static inline size_t align_up(size_t x) { return (x + 255) & ~(size_t)255; }

extern "C" void kernel_launch(void* const* d_in, const int* in_sizes, int n_in,
                              void* d_out, int out_size, void* d_ws, size_t ws_size,
                              hipStream_t stream) {
    const float* x     = (const float*)d_in[0];
    const int*   ei    = (const int*)d_in[1];
    const float* ew    = (const float*)d_in[2];
    const float* W_in  = (const float*)d_in[3];
    const float* b_in  = (const float*)d_in[4];
    const float* W_h1  = (const float*)d_in[5];
    const float* b_h1  = (const float*)d_in[6];
    const float* W_h2  = (const float*)d_in[7];
    const float* b_h2  = (const float*)d_in[8];
    const float* W_out = (const float*)d_in[9];
    const float* b_out = (const float*)d_in[10];

    const int* rows = ei;
    const int* cols = ei + N_EDGES;

    // workspace layout — ~65.1 MB (<= proven-safe 65.2); s2 lives in d_out
    char* w = (char*)d_ws;
    size_t off = 0;
    int* counts = (int*)(w + off);            off = align_up(off + (size_t)N_NODES * 4);   // reused as fill
    int* row_ptr= (int*)(w + off);            off = align_up(off + (size_t)(N_NODES + 1) * 4);
    int* bsum   = (int*)(w + off);            off = align_up(off + 512 * 4);
    int* ecol   = (int*)(w + off);            off = align_up(off + (size_t)N_EDGES * 4);
    u16* ewb    = (u16*)(w + off);            off = align_up(off + (size_t)N_EDGES * 2);
    u16* scnt   = (u16*)(w + off);            off = align_up(off + (size_t)N_NODES * NS * 2);
    u16* t1     = (u16*)(w + off);            off = align_up(off + (size_t)N_NODES * FEAT * 2);
    u16* h      = (u16*)(w + off);            off = align_up(off + (size_t)N_NODES * FEAT * 2);
    u16* Wp_in  = (u16*)(w + off);            off = align_up(off + (size_t)128 * 384 * 2);
    u16* Wp_h1  = (u16*)(w + off);            off = align_up(off + (size_t)128 * 384 * 2);
    u16* Wp_h2  = (u16*)(w + off);            off = align_up(off + (size_t)128 * 384 * 2);
    u16* Wp_out = (u16*)(w + off);            off = align_up(off + (size_t)64 * 384 * 2);
    u16* s2d    = (u16*)d_out;                // 100000*128 bf16 == 100000*64 f32 bytes

    hipMemsetAsync(counts, 0, (size_t)N_NODES * 4, stream);

    // weight prep + input conversion
    prep_w_kernel<<<(128 * 384 + 255) / 256, 256, 0, stream>>>(W_in, Wp_in, 128);
    prep_w_kernel<<<(128 * 384 + 255) / 256, 256, 0, stream>>>(W_h1, Wp_h1, 128);
    prep_w_kernel<<<(128 * 384 + 255) / 256, 256, 0, stream>>>(W_h2, Wp_h2, 128);
    prep_w_kernel<<<(64 * 384 + 255) / 256, 256, 0, stream>>>(W_out, Wp_out, 64);
    cvt_kernel<<<(N_NODES * FEAT / 4 + 255) / 256, 256, 0, stream>>>(x, h);

    // CSR build (counting sort) + per-row col sort + slice counts
    hist_kernel<<<N_EDGES / 256, 256, 0, stream>>>(rows, counts);
    reduce_counts_kernel<<<NB_SCAN, 256, 0, stream>>>(counts, bsum);
    scan_bsums_kernel<<<1, 512, 0, stream>>>(bsum, row_ptr);
    write_rowptr_kernel<<<NB_SCAN, 256, 0, stream>>>(counts, bsum, row_ptr);  // zeroes counts -> fill
    scatter_kernel<<<N_EDGES / 256, 256, 0, stream>>>(rows, cols, ew, row_ptr, counts, ecol, ewb);
    rowsort_kernel<<<N_NODES / 4, 256, 0, stream>>>(row_ptr, ecol, ewb, scnt);

    const int sweep_grid = (N_NODES / 32 + 3) / 4;   // 3125 waves -> 782 blocks (~1 cohort)
    const int gemm_grid  = N_NODES / 16;             // 6250 blocks

    // Layer 1: h = relu(cheb(x))
    sweep_kernel<<<sweep_grid, 256, 0, stream>>>(row_ptr, scnt, ecol, ewb, h, t1);
    sweep_kernel<<<sweep_grid, 256, 0, stream>>>(row_ptr, scnt, ecol, ewb, t1, s2d);
    gemm_kernel<128, true, false, false><<<gemm_grid, 256, 0, stream>>>(h, t1, s2d, Wp_in, b_in, h);

    // Layer 2: h = relu(cheb(h) + h)
    sweep_kernel<<<sweep_grid, 256, 0, stream>>>(row_ptr, scnt, ecol, ewb, h, t1);
    sweep_kernel<<<sweep_grid, 256, 0, stream>>>(row_ptr, scnt, ecol, ewb, t1, s2d);
    gemm_kernel<128, true, true, false><<<gemm_grid, 256, 0, stream>>>(h, t1, s2d, Wp_h1, b_h1, h);

    // Layer 3: h = relu(cheb(h) + h)
    sweep_kernel<<<sweep_grid, 256, 0, stream>>>(row_ptr, scnt, ecol, ewb, h, t1);
    sweep_kernel<<<sweep_grid, 256, 0, stream>>>(row_ptr, scnt, ecol, ewb, t1, s2d);
    gemm_kernel<128, true, true, false><<<gemm_grid, 256, 0, stream>>>(h, t1, s2d, Wp_h2, b_h2, h);

    // Layer 4: out = cheb(h)   (O = 64, f32 output; S2 aliases d_out — barrier-safe)
    sweep_kernel<<<sweep_grid, 256, 0, stream>>>(row_ptr, scnt, ecol, ewb, h, t1);
    sweep_kernel<<<sweep_grid, 256, 0, stream>>>(row_ptr, scnt, ecol, ewb, t1, s2d);
    gemm_kernel<64, false, false, true><<<gemm_grid, 256, 0, stream>>>(h, t1, s2d, Wp_out, b_out, d_out);
}